// Round 10
// baseline (178.889 us; speedup 1.0000x reference)
//
#include <hip/hip_runtime.h>
#include <stdint.h>

#define GAS __attribute__((address_space(1)))
#define LAS __attribute__((address_space(3)))

typedef unsigned short u16;
typedef __attribute__((ext_vector_type(8))) __bf16 bf16x8;
typedef __attribute__((ext_vector_type(4))) float f32x4;
typedef __attribute__((ext_vector_type(2))) unsigned int u32x2;
typedef __attribute__((ext_vector_type(4))) unsigned int u32x4;

#define SEQ 2048
#define WORD 1024
#define EMBED 128
#define NHEAD 16

__device__ __forceinline__ u16 f2b(float f) {
  return __builtin_bit_cast(u16, (__bf16)f);
}

__device__ __forceinline__ unsigned cvt_pk_bf16(float lo, float hi) {
  unsigned r;
  asm("v_cvt_pk_bf16_f32 %0, %1, %2" : "=v"(r) : "v"(lo), "v"(hi));
  return r;
}

// ---------------- fused prep: weight transposes + proj transpose + x cast ----
// 1-D grid, 6912 blocks of 256 thr:
//   [0,6144):   W{q,k,v} transpose+cast, z = bid>>7 (48 z), 32x4 tiles
//   [6144,6400): proj transpose+cast, 64x4 tiles
//   [6400,6912): x fp32->bf16 cast, 4096 elems/block
__global__ __launch_bounds__(256) void prep_kernel(
    const float* __restrict__ x, const float* __restrict__ Wq,
    const float* __restrict__ Wk, const float* __restrict__ Wv,
    const float* __restrict__ proj, u16* __restrict__ xb, u16* __restrict__ Wqt,
    u16* __restrict__ Wkt, u16* __restrict__ Wvt, u16* __restrict__ projT) {
  __shared__ float tile[32][33];
  const int bid = blockIdx.x;
  const int tid = threadIdx.x;
  const int tx = tid & 31, ty = tid >> 5;  // ty 0..7
  if (bid < 6144) {
    int z = bid >> 7, xy = bid & 127;  // 128 blocks per z (32 x 4)
    int bx = xy & 31, by = xy >> 5;
    int wsel = z >> 4, hh = z & 15;
    const float* s = (wsel == 0 ? Wq : wsel == 1 ? Wk : Wv) + (long)hh * (WORD * EMBED);
    u16* d = (wsel == 0 ? Wqt : wsel == 1 ? Wkt : Wvt) + (long)hh * (WORD * EMBED);
    int r0 = bx * 32, c0 = by * 32;
#pragma unroll
    for (int i = 0; i < 4; ++i)
      tile[ty + i * 8][tx] = s[(long)(r0 + ty + i * 8) * EMBED + c0 + tx];
    __syncthreads();
#pragma unroll
    for (int i = 0; i < 4; ++i)
      d[(long)(c0 + ty + i * 8) * WORD + r0 + tx] = f2b(tile[tx][ty + i * 8]);
  } else if (bid < 6400) {
    int idx = bid - 6144;  // 0..255 (64 x 4)
    int bx = idx & 63, by = idx >> 6;
    int r0 = bx * 32, c0 = by * 32;
#pragma unroll
    for (int i = 0; i < 4; ++i)
      tile[ty + i * 8][tx] = proj[(long)(r0 + ty + i * 8) * EMBED + c0 + tx];
    __syncthreads();
#pragma unroll
    for (int i = 0; i < 4; ++i)
      projT[(long)(c0 + ty + i * 8) * SEQ + r0 + tx] = f2b(tile[tx][ty + i * 8]);
  } else {
    long base = (long)(bid - 6400) * 4096;  // 512 blocks x 4096 floats
#pragma unroll
    for (int k = 0; k < 4; ++k) {
      long i = base + k * 1024 + tid * 4;
      float4 v = *(const float4*)(x + i);
      ushort4 o;
      o.x = f2b(v.x); o.y = f2b(v.y); o.z = f2b(v.z); o.w = f2b(v.w);
      *(ushort4*)(xb + i) = o;
    }
  }
}

// ---------------- generic 128x128-tile GEMM: C = (A·B^T + bias) * scale ----
// R7-proven form: single-buffered, full fragment preload, implicit multi-block
// overlap at 3 blocks/CU hides the staging drain. R8 (explicit dbuf @2/CU)
// and R9 (per-kc staging @4/CU, VGPR=64) both regressed — do not repeat.
// ATOMIC=true: epilogue atomicAdds fp32 into C (split-K merge without pbuf).
template <typename OUT, bool ATOMIC = false>
__device__ __forceinline__ void gemm128(const u16* __restrict__ A, const u16* __restrict__ B,
                                        OUT* __restrict__ C, int lda, int ldb, int ldc,
                                        int ksteps, const float* biasN, const float* biasM,
                                        float scale) {
  __shared__ u16 lA[128 * 64];
  __shared__ u16 lB[128 * 64];
  const int tid = threadIdx.x;
  const int l = tid & 63, w = tid >> 6;
  const int quad = l >> 4, ln = l & 15;
  const int wm = w >> 1, wn = w & 1;
  f32x4 acc[4][4] = {};
  for (int ks = 0; ks < ksteps; ++ks) {
    const u16* Ak = A + ks * 64;
    const u16* Bk = B + ks * 64;
    __syncthreads();  // prior-iter LDS reads complete before overwrite
#pragma unroll
    for (int i = 0; i < 4; ++i) {
      int idx = w * 256 + i * 64 + l;        // 16B-chunk index 0..1023
      int r = idx >> 3, cp = idx & 7;
      int cg = cp ^ (r & 7);                 // global chunk for this LDS slot
      __builtin_amdgcn_global_load_lds((const GAS void*)(Ak + (long)r * lda + cg * 8),
                                       (LAS void*)(lA + (w * 256 + i * 64) * 8), 16, 0, 0);
      __builtin_amdgcn_global_load_lds((const GAS void*)(Bk + (long)r * ldb + cg * 8),
                                       (LAS void*)(lB + (w * 256 + i * 64) * 8), 16, 0, 0);
    }
    __syncthreads();
    bf16x8 af[2][4], bfv[2][4];
#pragma unroll
    for (int kc = 0; kc < 2; ++kc) {
#pragma unroll
      for (int i = 0; i < 4; ++i) {
        int c = kc * 4 + quad;
        int rm = wm * 64 + i * 16 + ln;
        af[kc][i] = *(const bf16x8*)(lA + rm * 64 + ((c ^ (rm & 7)) * 8));
        int rn = wn * 64 + i * 16 + ln;
        bfv[kc][i] = *(const bf16x8*)(lB + rn * 64 + ((c ^ (rn & 7)) * 8));
      }
    }
#pragma unroll
    for (int kc = 0; kc < 2; ++kc)
#pragma unroll
      for (int i = 0; i < 4; ++i)
#pragma unroll
        for (int j = 0; j < 4; ++j)
          acc[i][j] = __builtin_amdgcn_mfma_f32_16x16x32_bf16(af[kc][i], bfv[kc][j],
                                                              acc[i][j], 0, 0, 0);
  }
  // epilogue: C row = wm*64+i*16+quad*4+reg, col = wn*64+j*16+ln (m89 C-layout)
#pragma unroll
  for (int i = 0; i < 4; ++i) {
#pragma unroll
    for (int j = 0; j < 4; ++j) {
      int row0 = wm * 64 + i * 16 + quad * 4;
      int col = wn * 64 + j * 16 + ln;
      float bn = biasN ? biasN[col] : 0.f;
#pragma unroll
      for (int reg = 0; reg < 4; ++reg) {
        int row = row0 + reg;
        float bm = biasM ? biasM[row] : 0.f;
        float v = (acc[i][j][reg] + bn + bm) * scale;
        if constexpr (ATOMIC)
          atomicAdd((float*)&C[(long)row * ldc + col], v);
        else if constexpr (sizeof(OUT) == 2)
          C[(long)row * ldc + col] = (OUT)f2b(v);
        else
          C[(long)row * ldc + col] = v;
      }
    }
  }
}

// ---------------- fused QKV projection (z: 0=Q,1=K,2=V^T) ----------------
// Q gets log2(e)/sqrt(E) folded in so attention can use exp2 directly.
// Group-locality swizzle: each XCD owns 6 consecutive (h,which) groups.
// (256,3): R7-proven occupancy point for this gemm128 structure.
__global__ __launch_bounds__(256, 3) void qkv_gemm_kernel(
    const u16* __restrict__ xb, const u16* __restrict__ Wqt, const u16* __restrict__ Wkt,
    const u16* __restrict__ Wvt, const float* __restrict__ bq, const float* __restrict__ bk,
    const float* __restrict__ bv, u16* __restrict__ Q, u16* __restrict__ Kb,
    u16* __restrict__ Vt) {
  const int lin = blockIdx.x + 16 * (blockIdx.y + 16 * blockIdx.z);
  const int s = (lin & 7) * 96 + (lin >> 3);
  const int t = s & 15;            // m-tile (n-tile for V)
  const int h = (s >> 4) & 15;
  const int which = s >> 8;
  const float qscale = 0.12753042123789493f;  // log2(e)/sqrt(128)
  if (which == 0) {
    gemm128<u16>(xb + t * 128 * WORD, Wqt + h * EMBED * WORD,
                 Q + h * SEQ * EMBED + t * 128 * EMBED, WORD, WORD, EMBED,
                 WORD / 64, bq + h * EMBED, nullptr, qscale);
  } else if (which == 1) {
    gemm128<u16>(xb + t * 128 * WORD, Wkt + h * EMBED * WORD,
                 Kb + h * SEQ * EMBED + t * 128 * EMBED, WORD, WORD, EMBED,
                 WORD / 64, bk + h * EMBED, nullptr, 1.f);
  } else {
    // V^T[e][s] = sum_w Wvt[h][e][w] * x[s][w]  (A=Wvt rows e, B=x rows s)
    gemm128<u16>(Wvt + h * EMBED * WORD, xb + t * 128 * WORD,
                 Vt + h * EMBED * SEQ + t * 128, WORD, WORD, SEQ,
                 WORD / 64, nullptr, bv + h * EMBED, 1.f);
  }
}

// ---------------- flash attention v6 (R5, proven 51.7 us) ----------------
__global__ __launch_bounds__(512, 2) void attn_kernel(const u16* __restrict__ Q,
                                                      const u16* __restrict__ K,
                                                      const u16* __restrict__ V,  // V^T [h][e][s]
                                                      u16* __restrict__ Zs) {
  __shared__ __align__(16) u16 lKV[2][32768];  // per buf: Ke|Ko (32K) Ve|Vo (32K)
  const int bid = blockIdx.x;
  const int swz = (bid & 7) * 32 + (bid >> 3);  // bijective, 2 heads per XCD
  const int h = swz >> 4, qb = swz & 15;        // qb: 128-row tile, 0..15
  const int tid = threadIdx.x;
  const int l = tid & 63, w = tid >> 6, quad = l >> 4, ln = l & 15;
  const int wr = w >> 1, wk = w & 1;            // row-group / key-group
  const u16* Qh = Q + h * SEQ * EMBED;
  const u16* Kh = K + h * SEQ * EMBED;
  const u16* Vh = V + h * EMBED * SEQ;
  const int q0 = qb * 128 + wr * 32;

  auto stage = [&](int buf, int sup) {
#pragma unroll
    for (int j = 0; j < 4; ++j) {
      int kb = j >> 1;                      // 0 = even 64-key tile, 1 = odd
      int cb = (j & 1) * 512 + w * 64;      // wave-uniform chunk base 0..1023
      int c = cb + l;
      int rk = c >> 4, cgk = (c & 15) ^ (rk & 15);
      __builtin_amdgcn_global_load_lds(
          (const GAS void*)(Kh + (sup * 128 + kb * 64 + rk) * EMBED + cgk * 8),
          (LAS void*)(&lKV[buf][kb * 8192 + cb * 8]), 16, 0, 0);
      int rv = c >> 3, cgv = (c & 7) ^ (rv & 7);
      __builtin_amdgcn_global_load_lds(
          (const GAS void*)(Vh + rv * SEQ + sup * 128 + kb * 64 + cgv * 8),
          (LAS void*)(&lKV[buf][16384 + kb * 8192 + cb * 8]), 16, 0, 0);
    }
  };

  // Q fragments in registers (frag layout: m/n=ln, k=quad*8+j); log2e/sqrt(E) folded
  bf16x8 qf[2][4];
#pragma unroll
  for (int rs = 0; rs < 2; ++rs)
#pragma unroll
    for (int kc = 0; kc < 4; ++kc)
      qf[rs][kc] = *(const bf16x8*)(Qh + (q0 + rs * 16 + ln) * EMBED + kc * 32 + quad * 8);

  f32x4 oacc[2][8] = {};
  float rsum[2] = {0.f, 0.f};

  stage(0, 0);  // prologue: 8 gll in flight

  int cur = 0;
#pragma unroll 1
  for (int sup = 0; sup < SEQ / 128; ++sup) {
    if (sup + 1 < SEQ / 128) {
      stage(cur ^ 1, sup + 1);
      asm volatile("s_waitcnt vmcnt(8)" ::: "memory");  // stage(sup) retired
    } else {
      asm volatile("s_waitcnt vmcnt(0)" ::: "memory");
    }
    __builtin_amdgcn_s_barrier();       // all waves' stage(sup) visible
    __builtin_amdgcn_sched_barrier(0);  // no ds_read hoisted above this point

    const u16* myK = &lKV[cur][wk * 8192];
    const u16* myV = &lKV[cur][16384 + wk * 8192];

    // ---- S^T = K'.Q (swapped): lane holds P[key=ns*16+quad*4+r][q=rs*16+ln] --
    f32x4 sacc[2][4] = {};
#pragma unroll
    for (int kc = 0; kc < 4; ++kc) {
      bf16x8 kf[4];
#pragma unroll
      for (int ns = 0; ns < 4; ++ns) {
        int kr = ns * 16 + ln;
        kf[ns] = *(const bf16x8*)(myK + kr * 128 + (((kc * 4 + quad) ^ (kr & 15)) * 8));
      }
      __builtin_amdgcn_s_setprio(1);
#pragma unroll
      for (int ns = 0; ns < 4; ++ns)
#pragma unroll
        for (int rs = 0; rs < 2; ++rs)
          sacc[rs][ns] = __builtin_amdgcn_mfma_f32_16x16x32_bf16(kf[ns], qf[rs][kc],
                                                                 sacc[rs][ns], 0, 0, 0);
      __builtin_amdgcn_s_setprio(0);
    }
    // ---- preload all V fragments from LDS (B-frag: n=e-row, k=key) ----
    bf16x8 vf[2][8];
#pragma unroll
    for (int kc = 0; kc < 2; ++kc)
#pragma unroll
      for (int es = 0; es < 8; ++es) {
        int er = es * 16 + ln;
        vf[kc][es] = *(const bf16x8*)(myV + er * 64 + (((kc * 4 + quad) ^ (er & 7)) * 8));
      }
    // ---- softmax + PA assembly + PV, fully in-register (validated R4/R5) ----
#pragma unroll
    for (int rs = 0; rs < 2; ++rs) {
      float p[4][4];
#pragma unroll
      for (int ns = 0; ns < 4; ++ns)
#pragma unroll
        for (int r = 0; r < 4; ++r) p[ns][r] = exp2f(sacc[rs][ns][r]);
      float s0 = (p[0][0] + p[0][1]) + (p[0][2] + p[0][3]);
      float s1 = (p[1][0] + p[1][1]) + (p[1][2] + p[1][3]);
      float s2 = (p[2][0] + p[2][1]) + (p[2][2] + p[2][3]);
      float s3 = (p[3][0] + p[3][1]) + (p[3][2] + p[3][3]);
      rsum[rs] += (s0 + s1) + (s2 + s3);
#pragma unroll
      for (int kc = 0; kc < 2; ++kc) {
        int n0 = kc * 2, n1 = kc * 2 + 1;
        unsigned a0 = cvt_pk_bf16(p[n0][0], p[n0][1]);
        unsigned a1 = cvt_pk_bf16(p[n0][2], p[n0][3]);
        unsigned b0 = cvt_pk_bf16(p[n1][0], p[n1][1]);
        unsigned b1 = cvt_pk_bf16(p[n1][2], p[n1][3]);
        u32x2 t0 = __builtin_amdgcn_permlane32_swap(a0, b0, false, false);
        u32x2 u0 = __builtin_amdgcn_permlane16_swap(t0.x, t0.y, false, false);
        u32x2 t1 = __builtin_amdgcn_permlane32_swap(a1, b1, false, false);
        u32x2 u1 = __builtin_amdgcn_permlane16_swap(t1.x, t1.y, false, false);
        u32x4 paw = {u0.x, u1.x, u0.y, u1.y};
        bf16x8 pa = __builtin_bit_cast(bf16x8, paw);
        __builtin_amdgcn_s_setprio(1);
#pragma unroll
        for (int es = 0; es < 8; ++es)
          oacc[rs][es] = __builtin_amdgcn_mfma_f32_16x16x32_bf16(pa, vf[kc][es],
                                                                 oacc[rs][es], 0, 0, 0);
        __builtin_amdgcn_s_setprio(0);
      }
    }
    __builtin_amdgcn_sched_barrier(0);
    __builtin_amdgcn_s_barrier();  // all waves done reading lKV[cur]
    cur ^= 1;
  }

  // ---- rowsum: reduce over quads (q=ln), broadcast to oacc row alignment ----
  float srl[2][4];
#pragma unroll
  for (int rs = 0; rs < 2; ++rs) {
    float t = rsum[rs] + __shfl(rsum[rs], l ^ 16);
    t = t + __shfl(t, l ^ 32);
#pragma unroll
    for (int r = 0; r < 4; ++r) srl[rs][r] = __shfl(t, quad * 4 + r);
  }

  // ---- merge wk=1 into wk=0 via LDS (reuses lKV), divide by l, store ----
  __syncthreads();
  float* lO = (float*)lKV;  // [wr][32][132] fp32, wr 0..3 -> 67.6 KB
  if (wk == 1) {
#pragma unroll
    for (int rs = 0; rs < 2; ++rs) {
#pragma unroll
      for (int es = 0; es < 8; ++es)
#pragma unroll
        for (int r = 0; r < 4; ++r)
          lO[wr * 4224 + (rs * 16 + quad * 4 + r) * 132 + es * 16 + ln] = oacc[rs][es][r];
      if (ln == 0)
#pragma unroll
        for (int r = 0; r < 4; ++r)
          lO[wr * 4224 + (rs * 16 + quad * 4 + r) * 132 + 128] = srl[rs][r];
    }
  }
  __syncthreads();
  if (wk == 0) {
#pragma unroll
    for (int rs = 0; rs < 2; ++rs)
#pragma unroll
      for (int r = 0; r < 4; ++r) {
        int lrow = rs * 16 + quad * 4 + r;
        float lsum = srl[rs][r] + lO[wr * 4224 + lrow * 132 + 128];
        float rl = 1.f / lsum;
        int srow = q0 + lrow;
#pragma unroll
        for (int es = 0; es < 8; ++es) {
          float o = oacc[rs][es][r] + lO[wr * 4224 + lrow * 132 + es * 16 + ln];
          Zs[(long)srow * (NHEAD * EMBED) + h * EMBED + es * 16 + ln] = f2b(o * rl);
        }
      }
  }
}

// ---------------- out += Zs · proj (split-K=8, fp32 atomics, no pbuf) ------
__global__ __launch_bounds__(256, 2) void final_gemm_kernel(const u16* __restrict__ Zs,
                                                            const u16* __restrict__ projT,
                                                            float* __restrict__ out) {
  const int t = blockIdx.x;   // m-tile 0..15
  const int kc = blockIdx.y;  // k-chunk 0..7 (256 wide)
  gemm128<float, true>(Zs + (long)t * 128 * (NHEAD * EMBED) + kc * 256, projT + kc * 256,
                       out + (long)t * 128 * EMBED,
                       NHEAD * EMBED, NHEAD * EMBED, EMBED, 4, nullptr, nullptr, 1.f);
}

extern "C" void kernel_launch(void* const* d_in, const int* in_sizes, int n_in,
                              void* d_out, int out_size, void* d_ws, size_t ws_size,
                              hipStream_t stream) {
  const float* x    = (const float*)d_in[0];
  const float* Wq   = (const float*)d_in[1];
  const float* bq   = (const float*)d_in[2];
  const float* Wk   = (const float*)d_in[3];
  const float* bk   = (const float*)d_in[4];
  const float* Wv   = (const float*)d_in[5];
  const float* bv   = (const float*)d_in[6];
  const float* proj = (const float*)d_in[7];
  float* out = (float*)d_out;

  char* ws = (char*)d_ws;
  // workspace layout (MiB offsets): total 52 MiB.
  u16* xb    = (u16*)(ws);                      // 2048x1024 bf16       (4 MiB)
  u16* Wqt   = (u16*)(ws + (4L << 20));         // [16][128][1024]      (4 MiB)
  u16* Wkt   = (u16*)(ws + (8L << 20));         //                      (4 MiB)
  u16* Wvt   = (u16*)(ws + (12L << 20));        //                      (4 MiB)
  u16* projT = (u16*)(ws + (16L << 20));        // [128][2048]          (0.5 MiB)
  u16* Qm    = (u16*)(ws + (17L << 20));        // [16][2048][128]      (8 MiB)
  u16* Km    = (u16*)(ws + (26L << 20));        // [16][2048][128]      (8 MiB)
  u16* Vt    = (u16*)(ws + (35L << 20));        // [16][128][2048]      (8 MiB)
  u16* Zs    = (u16*)(ws + (44L << 20));        // [2048][2048]         (8 MiB)

  // zero out for split-K atomic accumulation (own memset — do not rely on
  // harness re-poison semantics)
  hipMemsetAsync(out, 0, (size_t)SEQ * EMBED * sizeof(float), stream);

  // fused prep: all transposes + x cast in one dispatch
  prep_kernel<<<dim3(6912), dim3(256), 0, stream>>>(x, Wq, Wk, Wv, proj, xb, Wqt,
                                                    Wkt, Wvt, projT);

  qkv_gemm_kernel<<<dim3(16, NHEAD, 3), dim3(256), 0, stream>>>(
      xb, Wqt, Wkt, Wvt, bq, bk, bv, Qm, Km, Vt);

  attn_kernel<<<dim3(256), dim3(512), 0, stream>>>(Qm, Km, Vt, Zs);

  final_gemm_kernel<<<dim3(16, 8), dim3(256), 0, stream>>>(Zs, projT, out);
}

// Round 11
// 175.828 us; speedup vs baseline: 1.0174x; 1.0174x over previous
//
#include <hip/hip_runtime.h>
#include <stdint.h>

#define GAS __attribute__((address_space(1)))
#define LAS __attribute__((address_space(3)))

typedef unsigned short u16;
typedef __attribute__((ext_vector_type(8))) __bf16 bf16x8;
typedef __attribute__((ext_vector_type(4))) float f32x4;
typedef __attribute__((ext_vector_type(2))) unsigned int u32x2;
typedef __attribute__((ext_vector_type(4))) unsigned int u32x4;

#define SEQ 2048
#define WORD 1024
#define EMBED 128
#define NHEAD 16

__device__ __forceinline__ u16 f2b(float f) {
  return __builtin_bit_cast(u16, (__bf16)f);
}

__device__ __forceinline__ unsigned cvt_pk_bf16(float lo, float hi) {
  unsigned r;
  asm("v_cvt_pk_bf16_f32 %0, %1, %2" : "=v"(r) : "v"(lo), "v"(hi));
  return r;
}

// ---------------- fused prep: weight transposes + proj transpose + x cast ----
// 1-D grid, 6912 blocks of 256 thr:
//   [0,6144):   W{q,k,v} transpose+cast, z = bid>>7 (48 z), 32x4 tiles
//   [6144,6400): proj transpose+cast, 64x4 tiles
//   [6400,6912): x fp32->bf16 cast, 4096 elems/block
__global__ __launch_bounds__(256) void prep_kernel(
    const float* __restrict__ x, const float* __restrict__ Wq,
    const float* __restrict__ Wk, const float* __restrict__ Wv,
    const float* __restrict__ proj, u16* __restrict__ xb, u16* __restrict__ Wqt,
    u16* __restrict__ Wkt, u16* __restrict__ Wvt, u16* __restrict__ projT) {
  __shared__ float tile[32][33];
  const int bid = blockIdx.x;
  const int tid = threadIdx.x;
  const int tx = tid & 31, ty = tid >> 5;  // ty 0..7
  if (bid < 6144) {
    int z = bid >> 7, xy = bid & 127;  // 128 blocks per z (32 x 4)
    int bx = xy & 31, by = xy >> 5;
    int wsel = z >> 4, hh = z & 15;
    const float* s = (wsel == 0 ? Wq : wsel == 1 ? Wk : Wv) + (long)hh * (WORD * EMBED);
    u16* d = (wsel == 0 ? Wqt : wsel == 1 ? Wkt : Wvt) + (long)hh * (WORD * EMBED);
    int r0 = bx * 32, c0 = by * 32;
#pragma unroll
    for (int i = 0; i < 4; ++i)
      tile[ty + i * 8][tx] = s[(long)(r0 + ty + i * 8) * EMBED + c0 + tx];
    __syncthreads();
#pragma unroll
    for (int i = 0; i < 4; ++i)
      d[(long)(c0 + ty + i * 8) * WORD + r0 + tx] = f2b(tile[tx][ty + i * 8]);
  } else if (bid < 6400) {
    int idx = bid - 6144;  // 0..255 (64 x 4)
    int bx = idx & 63, by = idx >> 6;
    int r0 = bx * 32, c0 = by * 32;
#pragma unroll
    for (int i = 0; i < 4; ++i)
      tile[ty + i * 8][tx] = proj[(long)(r0 + ty + i * 8) * EMBED + c0 + tx];
    __syncthreads();
#pragma unroll
    for (int i = 0; i < 4; ++i)
      projT[(long)(c0 + ty + i * 8) * SEQ + r0 + tx] = f2b(tile[tx][ty + i * 8]);
  } else {
    long base = (long)(bid - 6400) * 4096;  // 512 blocks x 4096 floats
#pragma unroll
    for (int k = 0; k < 4; ++k) {
      long i = base + k * 1024 + tid * 4;
      float4 v = *(const float4*)(x + i);
      ushort4 o;
      o.x = f2b(v.x); o.y = f2b(v.y); o.z = f2b(v.z); o.w = f2b(v.w);
      *(ushort4*)(xb + i) = o;
    }
  }
}

// ---------------- generic 128x128-tile GEMM: C = (A·B^T + bias) * scale ----
// R7-proven form: single-buffered, full fragment preload, implicit multi-block
// overlap at 3 blocks/CU hides the staging drain. Session lessons pinned here:
// R8 explicit dbuf @2 blocks/CU = -17 us (m132 pattern); R9 per-kc staging
// @4 blocks/CU (VGPR=64, AGPR split) = -7 us; R10 atomic split-K merge = -7 us
// (2.1M contended scalar atomics beat by the pbuf round-trip). Do not repeat.
template <typename OUT>
__device__ __forceinline__ void gemm128(const u16* __restrict__ A, const u16* __restrict__ B,
                                        OUT* __restrict__ C, int lda, int ldb, int ldc,
                                        int ksteps, const float* biasN, const float* biasM,
                                        float scale) {
  __shared__ u16 lA[128 * 64];
  __shared__ u16 lB[128 * 64];
  const int tid = threadIdx.x;
  const int l = tid & 63, w = tid >> 6;
  const int quad = l >> 4, ln = l & 15;
  const int wm = w >> 1, wn = w & 1;
  f32x4 acc[4][4] = {};
  for (int ks = 0; ks < ksteps; ++ks) {
    const u16* Ak = A + ks * 64;
    const u16* Bk = B + ks * 64;
    __syncthreads();  // prior-iter LDS reads complete before overwrite
#pragma unroll
    for (int i = 0; i < 4; ++i) {
      int idx = w * 256 + i * 64 + l;        // 16B-chunk index 0..1023
      int r = idx >> 3, cp = idx & 7;
      int cg = cp ^ (r & 7);                 // global chunk for this LDS slot
      __builtin_amdgcn_global_load_lds((const GAS void*)(Ak + (long)r * lda + cg * 8),
                                       (LAS void*)(lA + (w * 256 + i * 64) * 8), 16, 0, 0);
      __builtin_amdgcn_global_load_lds((const GAS void*)(Bk + (long)r * ldb + cg * 8),
                                       (LAS void*)(lB + (w * 256 + i * 64) * 8), 16, 0, 0);
    }
    __syncthreads();
    bf16x8 af[2][4], bfv[2][4];
#pragma unroll
    for (int kc = 0; kc < 2; ++kc) {
#pragma unroll
      for (int i = 0; i < 4; ++i) {
        int c = kc * 4 + quad;
        int rm = wm * 64 + i * 16 + ln;
        af[kc][i] = *(const bf16x8*)(lA + rm * 64 + ((c ^ (rm & 7)) * 8));
        int rn = wn * 64 + i * 16 + ln;
        bfv[kc][i] = *(const bf16x8*)(lB + rn * 64 + ((c ^ (rn & 7)) * 8));
      }
    }
#pragma unroll
    for (int kc = 0; kc < 2; ++kc)
#pragma unroll
      for (int i = 0; i < 4; ++i)
#pragma unroll
        for (int j = 0; j < 4; ++j)
          acc[i][j] = __builtin_amdgcn_mfma_f32_16x16x32_bf16(af[kc][i], bfv[kc][j],
                                                              acc[i][j], 0, 0, 0);
  }
  // epilogue: C row = wm*64+i*16+quad*4+reg, col = wn*64+j*16+ln (m89 C-layout)
#pragma unroll
  for (int i = 0; i < 4; ++i) {
#pragma unroll
    for (int j = 0; j < 4; ++j) {
      int row0 = wm * 64 + i * 16 + quad * 4;
      int col = wn * 64 + j * 16 + ln;
      float bn = biasN ? biasN[col] : 0.f;
#pragma unroll
      for (int reg = 0; reg < 4; ++reg) {
        int row = row0 + reg;
        float bm = biasM ? biasM[row] : 0.f;
        float v = (acc[i][j][reg] + bn + bm) * scale;
        if constexpr (sizeof(OUT) == 2)
          C[(long)row * ldc + col] = (OUT)f2b(v);
        else
          C[(long)row * ldc + col] = v;
      }
    }
  }
}

// ---------------- fused QKV projection (z: 0=Q,1=K,2=V^T) ----------------
// Q gets log2(e)/sqrt(E) folded in so attention can use exp2 directly.
// Group-locality swizzle: each XCD owns 6 consecutive (h,which) groups.
__global__ __launch_bounds__(256, 3) void qkv_gemm_kernel(
    const u16* __restrict__ xb, const u16* __restrict__ Wqt, const u16* __restrict__ Wkt,
    const u16* __restrict__ Wvt, const float* __restrict__ bq, const float* __restrict__ bk,
    const float* __restrict__ bv, u16* __restrict__ Q, u16* __restrict__ Kb,
    u16* __restrict__ Vt) {
  const int lin = blockIdx.x + 16 * (blockIdx.y + 16 * blockIdx.z);
  const int s = (lin & 7) * 96 + (lin >> 3);
  const int t = s & 15;            // m-tile (n-tile for V)
  const int h = (s >> 4) & 15;
  const int which = s >> 8;
  const float qscale = 0.12753042123789493f;  // log2(e)/sqrt(128)
  if (which == 0) {
    gemm128<u16>(xb + t * 128 * WORD, Wqt + h * EMBED * WORD,
                 Q + h * SEQ * EMBED + t * 128 * EMBED, WORD, WORD, EMBED,
                 WORD / 64, bq + h * EMBED, nullptr, qscale);
  } else if (which == 1) {
    gemm128<u16>(xb + t * 128 * WORD, Wkt + h * EMBED * WORD,
                 Kb + h * SEQ * EMBED + t * 128 * EMBED, WORD, WORD, EMBED,
                 WORD / 64, bk + h * EMBED, nullptr, 1.f);
  } else {
    // V^T[e][s] = sum_w Wvt[h][e][w] * x[s][w]  (A=Wvt rows e, B=x rows s)
    gemm128<u16>(Wvt + h * EMBED * WORD, xb + t * 128 * WORD,
                 Vt + h * EMBED * SEQ + t * 128, WORD, WORD, SEQ,
                 WORD / 64, nullptr, bv + h * EMBED, 1.f);
  }
}

// ---------------- flash attention v6 (R5-proven, ~52 us) ----------------
// 8-wave blocks (4 row-groups x 2 key-groups), 128-key superiter, K+V LDS
// double buffer (128 KB), counted vmcnt(8), swapped QK^T with in-register
// exp2 + rowsum + cvt_pk/permlane PA assembly, XCD swizzle, merge epilogue.
// R6 lesson: 64-key superiter (2 blocks/CU) is SLOWER — ~400 cyc fixed
// overhead per superiter dominates; 128-key tiles amortize it best.
__global__ __launch_bounds__(512, 2) void attn_kernel(const u16* __restrict__ Q,
                                                      const u16* __restrict__ K,
                                                      const u16* __restrict__ V,  // V^T [h][e][s]
                                                      u16* __restrict__ Zs) {
  __shared__ __align__(16) u16 lKV[2][32768];  // per buf: Ke|Ko (32K) Ve|Vo (32K)
  const int bid = blockIdx.x;
  const int swz = (bid & 7) * 32 + (bid >> 3);  // bijective, 2 heads per XCD
  const int h = swz >> 4, qb = swz & 15;        // qb: 128-row tile, 0..15
  const int tid = threadIdx.x;
  const int l = tid & 63, w = tid >> 6, quad = l >> 4, ln = l & 15;
  const int wr = w >> 1, wk = w & 1;            // row-group / key-group
  const u16* Qh = Q + h * SEQ * EMBED;
  const u16* Kh = K + h * SEQ * EMBED;
  const u16* Vh = V + h * EMBED * SEQ;
  const int q0 = qb * 128 + wr * 32;

  auto stage = [&](int buf, int sup) {
#pragma unroll
    for (int j = 0; j < 4; ++j) {
      int kb = j >> 1;                      // 0 = even 64-key tile, 1 = odd
      int cb = (j & 1) * 512 + w * 64;      // wave-uniform chunk base 0..1023
      int c = cb + l;
      int rk = c >> 4, cgk = (c & 15) ^ (rk & 15);
      __builtin_amdgcn_global_load_lds(
          (const GAS void*)(Kh + (sup * 128 + kb * 64 + rk) * EMBED + cgk * 8),
          (LAS void*)(&lKV[buf][kb * 8192 + cb * 8]), 16, 0, 0);
      int rv = c >> 3, cgv = (c & 7) ^ (rv & 7);
      __builtin_amdgcn_global_load_lds(
          (const GAS void*)(Vh + rv * SEQ + sup * 128 + kb * 64 + cgv * 8),
          (LAS void*)(&lKV[buf][16384 + kb * 8192 + cb * 8]), 16, 0, 0);
    }
  };

  // Q fragments in registers (frag layout: m/n=ln, k=quad*8+j); log2e/sqrt(E) folded
  bf16x8 qf[2][4];
#pragma unroll
  for (int rs = 0; rs < 2; ++rs)
#pragma unroll
    for (int kc = 0; kc < 4; ++kc)
      qf[rs][kc] = *(const bf16x8*)(Qh + (q0 + rs * 16 + ln) * EMBED + kc * 32 + quad * 8);

  f32x4 oacc[2][8] = {};
  float rsum[2] = {0.f, 0.f};

  stage(0, 0);  // prologue: 8 gll in flight

  int cur = 0;
#pragma unroll 1
  for (int sup = 0; sup < SEQ / 128; ++sup) {
    if (sup + 1 < SEQ / 128) {
      stage(cur ^ 1, sup + 1);
      asm volatile("s_waitcnt vmcnt(8)" ::: "memory");  // stage(sup) retired
    } else {
      asm volatile("s_waitcnt vmcnt(0)" ::: "memory");
    }
    __builtin_amdgcn_s_barrier();       // all waves' stage(sup) visible
    __builtin_amdgcn_sched_barrier(0);  // no ds_read hoisted above this point

    const u16* myK = &lKV[cur][wk * 8192];
    const u16* myV = &lKV[cur][16384 + wk * 8192];

    // ---- S^T = K'.Q (swapped): lane holds P[key=ns*16+quad*4+r][q=rs*16+ln] --
    f32x4 sacc[2][4] = {};
#pragma unroll
    for (int kc = 0; kc < 4; ++kc) {
      bf16x8 kf[4];
#pragma unroll
      for (int ns = 0; ns < 4; ++ns) {
        int kr = ns * 16 + ln;
        kf[ns] = *(const bf16x8*)(myK + kr * 128 + (((kc * 4 + quad) ^ (kr & 15)) * 8));
      }
      __builtin_amdgcn_s_setprio(1);
#pragma unroll
      for (int ns = 0; ns < 4; ++ns)
#pragma unroll
        for (int rs = 0; rs < 2; ++rs)
          sacc[rs][ns] = __builtin_amdgcn_mfma_f32_16x16x32_bf16(kf[ns], qf[rs][kc],
                                                                 sacc[rs][ns], 0, 0, 0);
      __builtin_amdgcn_s_setprio(0);
    }
    // ---- preload all V fragments from LDS (B-frag: n=e-row, k=key) ----
    bf16x8 vf[2][8];
#pragma unroll
    for (int kc = 0; kc < 2; ++kc)
#pragma unroll
      for (int es = 0; es < 8; ++es) {
        int er = es * 16 + ln;
        vf[kc][es] = *(const bf16x8*)(myV + er * 64 + (((kc * 4 + quad) ^ (er & 7)) * 8));
      }
    // ---- softmax + PA assembly + PV, fully in-register (validated R4/R5) ----
#pragma unroll
    for (int rs = 0; rs < 2; ++rs) {
      float p[4][4];
#pragma unroll
      for (int ns = 0; ns < 4; ++ns)
#pragma unroll
        for (int r = 0; r < 4; ++r) p[ns][r] = exp2f(sacc[rs][ns][r]);
      float s0 = (p[0][0] + p[0][1]) + (p[0][2] + p[0][3]);
      float s1 = (p[1][0] + p[1][1]) + (p[1][2] + p[1][3]);
      float s2 = (p[2][0] + p[2][1]) + (p[2][2] + p[2][3]);
      float s3 = (p[3][0] + p[3][1]) + (p[3][2] + p[3][3]);
      rsum[rs] += (s0 + s1) + (s2 + s3);
#pragma unroll
      for (int kc = 0; kc < 2; ++kc) {
        // ns0 = kc*2 ("a" = keys [kc*32, kc*32+16)), ns1 = kc*2+1 ("b").
        // t = permlane32_swap(a, b); u = permlane16_swap(t.x, t.y):
        // u.x = [a@q0,a@q2,b@q0,b@q2], u.y = [a@q1,a@q3,b@q1,b@q3].
        int n0 = kc * 2, n1 = kc * 2 + 1;
        unsigned a0 = cvt_pk_bf16(p[n0][0], p[n0][1]);
        unsigned a1 = cvt_pk_bf16(p[n0][2], p[n0][3]);
        unsigned b0 = cvt_pk_bf16(p[n1][0], p[n1][1]);
        unsigned b1 = cvt_pk_bf16(p[n1][2], p[n1][3]);
        u32x2 t0 = __builtin_amdgcn_permlane32_swap(a0, b0, false, false);
        u32x2 u0 = __builtin_amdgcn_permlane16_swap(t0.x, t0.y, false, false);
        u32x2 t1 = __builtin_amdgcn_permlane32_swap(a1, b1, false, false);
        u32x2 u1 = __builtin_amdgcn_permlane16_swap(t1.x, t1.y, false, false);
        u32x4 paw = {u0.x, u1.x, u0.y, u1.y};
        bf16x8 pa = __builtin_bit_cast(bf16x8, paw);
        __builtin_amdgcn_s_setprio(1);
#pragma unroll
        for (int es = 0; es < 8; ++es)
          oacc[rs][es] = __builtin_amdgcn_mfma_f32_16x16x32_bf16(pa, vf[kc][es],
                                                                 oacc[rs][es], 0, 0, 0);
        __builtin_amdgcn_s_setprio(0);
      }
    }
    __builtin_amdgcn_sched_barrier(0);
    __builtin_amdgcn_s_barrier();  // all waves done reading lKV[cur]
    cur ^= 1;
  }

  // ---- rowsum: reduce over quads (q=ln), broadcast to oacc row alignment ----
  float srl[2][4];
#pragma unroll
  for (int rs = 0; rs < 2; ++rs) {
    float t = rsum[rs] + __shfl(rsum[rs], l ^ 16);
    t = t + __shfl(t, l ^ 32);
#pragma unroll
    for (int r = 0; r < 4; ++r) srl[rs][r] = __shfl(t, quad * 4 + r);
  }

  // ---- merge wk=1 into wk=0 via LDS (reuses lKV), divide by l, store ----
  __syncthreads();
  float* lO = (float*)lKV;  // [wr][32][132] fp32, wr 0..3 -> 67.6 KB
  if (wk == 1) {
#pragma unroll
    for (int rs = 0; rs < 2; ++rs) {
#pragma unroll
      for (int es = 0; es < 8; ++es)
#pragma unroll
        for (int r = 0; r < 4; ++r)
          lO[wr * 4224 + (rs * 16 + quad * 4 + r) * 132 + es * 16 + ln] = oacc[rs][es][r];
      if (ln == 0)
#pragma unroll
        for (int r = 0; r < 4; ++r)
          lO[wr * 4224 + (rs * 16 + quad * 4 + r) * 132 + 128] = srl[rs][r];
    }
  }
  __syncthreads();
  if (wk == 0) {
#pragma unroll
    for (int rs = 0; rs < 2; ++rs)
#pragma unroll
      for (int r = 0; r < 4; ++r) {
        int lrow = rs * 16 + quad * 4 + r;
        float lsum = srl[rs][r] + lO[wr * 4224 + lrow * 132 + 128];
        float rl = 1.f / lsum;
        int srow = q0 + lrow;
#pragma unroll
        for (int es = 0; es < 8; ++es) {
          float o = oacc[rs][es][r] + lO[wr * 4224 + lrow * 132 + es * 16 + ln];
          Zs[(long)srow * (NHEAD * EMBED) + h * EMBED + es * 16 + ln] = f2b(o * rl);
        }
      }
  }
}

// ---------------- out = Zs · proj, split-K=8 into partials ----------------
__global__ __launch_bounds__(256, 2) void final_gemm_kernel(const u16* __restrict__ Zs,
                                                            const u16* __restrict__ projT,
                                                            float* __restrict__ pbuf) {
  const int t = blockIdx.x;   // m-tile 0..15
  const int kc = blockIdx.y;  // k-chunk 0..7 (256 wide)
  gemm128<float>(Zs + (long)t * 128 * (NHEAD * EMBED) + kc * 256, projT + kc * 256,
                 pbuf + (long)kc * SEQ * EMBED + t * 128 * EMBED,
                 NHEAD * EMBED, NHEAD * EMBED, EMBED, 4, nullptr, nullptr, 1.f);
}

__global__ __launch_bounds__(256) void reduce_kernel(const float* __restrict__ pbuf,
                                                     float* __restrict__ out) {
  int i = (blockIdx.x * 256 + threadIdx.x) * 4;
  float4 s = {0.f, 0.f, 0.f, 0.f};
#pragma unroll
  for (int kc = 0; kc < 8; ++kc) {
    float4 v = *(const float4*)(pbuf + (long)kc * SEQ * EMBED + i);
    s.x += v.x; s.y += v.y; s.z += v.z; s.w += v.w;
  }
  *(float4*)(out + i) = s;
}

extern "C" void kernel_launch(void* const* d_in, const int* in_sizes, int n_in,
                              void* d_out, int out_size, void* d_ws, size_t ws_size,
                              hipStream_t stream) {
  const float* x    = (const float*)d_in[0];
  const float* Wq   = (const float*)d_in[1];
  const float* bq   = (const float*)d_in[2];
  const float* Wk   = (const float*)d_in[3];
  const float* bk   = (const float*)d_in[4];
  const float* Wv   = (const float*)d_in[5];
  const float* bv   = (const float*)d_in[6];
  const float* proj = (const float*)d_in[7];
  float* out = (float*)d_out;

  char* ws = (char*)d_ws;
  // workspace layout (MiB offsets): total 52 MiB.
  // pbuf (8 MiB fp32 partials) aliases xb+Wqt, which are dead after qkv_gemm.
  u16* xb    = (u16*)(ws);                      // 2048x1024 bf16       (4 MiB)
  u16* Wqt   = (u16*)(ws + (4L << 20));         // [16][128][1024]      (4 MiB)
  u16* Wkt   = (u16*)(ws + (8L << 20));         //                      (4 MiB)
  u16* Wvt   = (u16*)(ws + (12L << 20));        //                      (4 MiB)
  u16* projT = (u16*)(ws + (16L << 20));        // [128][2048]          (0.5 MiB)
  u16* Qm    = (u16*)(ws + (17L << 20));        // [16][2048][128]      (8 MiB)
  u16* Km    = (u16*)(ws + (26L << 20));        // [16][2048][128]      (8 MiB)
  u16* Vt    = (u16*)(ws + (35L << 20));        // [16][128][2048]      (8 MiB)
  u16* Zs    = (u16*)(ws + (44L << 20));        // [2048][2048]         (8 MiB)
  float* pbuf = (float*)(ws);                   // [8][2048][128] fp32  (8 MiB, aliased)

  // fused prep: all transposes + x cast in one dispatch
  prep_kernel<<<dim3(6912), dim3(256), 0, stream>>>(x, Wq, Wk, Wv, proj, xb, Wqt,
                                                    Wkt, Wvt, projT);

  qkv_gemm_kernel<<<dim3(16, NHEAD, 3), dim3(256), 0, stream>>>(
      xb, Wqt, Wkt, Wvt, bq, bk, bv, Qm, Km, Vt);

  attn_kernel<<<dim3(256), dim3(512), 0, stream>>>(Qm, Km, Vt, Zs);

  final_gemm_kernel<<<dim3(16, 8), dim3(256), 0, stream>>>(Zs, projT, pbuf);
  reduce_kernel<<<dim3(SEQ * EMBED / 1024), dim3(256), 0, stream>>>(pbuf, out);
}